// Round 4
// baseline (958.077 us; speedup 1.0000x reference)
//
#include <hip/hip_runtime.h>
#include <math.h>

#define Bb   2
#define CIN  32
#define Gg   4
#define NH   4
#define Hh   28
#define Ww   28
#define HW   784
#define Pp   7
#define PP   49
#define MID  48
#define COUT 64
#define OC   192   // MID*NH

// workspace offsets (floats); Q/K/V/O all [bh][g][ij][c] row-major
#define QOFF  0
#define KOFF  1204224
#define VOFF  2408448
#define OOFF  3612672

#define INV_SQN 0.17677669529663687f

// small precomputed tables (recomputed every call by the table block of qkvpe)
__device__ float g_peT[Gg * 32 * PP];   // [v][c(0..31)][kl], pre-scaled by 1/sqrt(32)
__device__ float g_geT[16 * 64];        // [c][v*16+g*4+m],  pre-scaled by 1/sqrt(32)
__device__ float g_WT2[OC * COUT];      // [h*48+c][o], permuted Wout

__device__ __forceinline__ unsigned bf16rne(float f) {
    unsigned u = __float_as_uint(f);
    return (u + 0x7fffu + ((u >> 16) & 1u)) >> 16;
}
__device__ __forceinline__ unsigned pack2(float a, float b) {
    return bf16rne(a) | (bf16rne(b) << 16);
}

// ---------------------------------------------------------------- kernel 1
// fused QKV 1x1 conv (blocks 0..223) + table setup (block 224)
__global__ __launch_bounds__(192) void qkvpe_kernel(const float* __restrict__ x,
    const float* __restrict__ Wq, const float* __restrict__ bq,
    const float* __restrict__ Wk, const float* __restrict__ bk,
    const float* __restrict__ Wv, const float* __restrict__ bv,
    const float* row_w1, const float* row_b1,
    const float* row_g,  const float* row_bb,
    const float* row_w2, const float* row_b2,
    const float* col_w1, const float* col_b1,
    const float* col_g,  const float* col_bb,
    const float* col_w2, const float* col_b2,
    const float* row_idx, const float* col_idx,
    const float* group_emb, const int* g_indices,
    const float* Wout,
    float* __restrict__ ws)
{
    int tid = threadIdx.x;
    if (blockIdx.x == Bb * Gg * Hh) {
        // ---------------- table block ----------------
        for (int t = tid; t < 2 * Gg * PP; t += 192) {
            int half = t / (Gg * PP);
            int n    = t - half * (Gg * PP);      // v*49 + kl
            int v = n / PP, kl = n % PP;
            const float* w1 = half ? col_w1 : row_w1;
            const float* b1 = half ? col_b1 : row_b1;
            const float* lg = half ? col_g  : row_g;
            const float* lb = half ? col_bb : row_bb;
            const float* w2 = half ? col_w2 : row_w2;
            const float* b2 = half ? col_b2 : row_b2;
            float tv = half ? col_idx[n] : row_idx[n];

            float hb[16];
            float mean = 0.f;
            for (int k = 0; k < 16; k++) { hb[k] = tv * w1[k] + b1[k]; mean += hb[k]; }
            mean *= (1.f / 16.f);
            float var = 0.f;
            for (int k = 0; k < 16; k++) { float d = hb[k] - mean; var += d * d; }
            var *= (1.f / 16.f);
            float inv = 1.f / sqrtf(var + 1e-5f);
            for (int k = 0; k < 16; k++) {
                float hn = (hb[k] - mean) * inv * lg[k] + lb[k];
                hb[k] = hn / (1.f + expf(-hn));
            }
            for (int p = 0; p < 16; p++) {
                float acc = b2[p];
                for (int k = 0; k < 16; k++) acc += hb[k] * w2[p * 16 + k];
                g_peT[(v * 32 + half * 16 + p) * PP + kl] = acc * INV_SQN;
            }
        }
        for (int t = tid; t < 64; t += 192) {
            int gi = g_indices[t];
            for (int c = 0; c < 16; c++)
                g_geT[c * 64 + t] = group_emb[gi * 16 + c] * INV_SQN;
        }
        for (int idx = tid; idx < OC * COUT; idx += 192) {
            int tp = idx >> 6, o = idx & 63;      // tp = h*48+c
            int h = tp / MID, c = tp % MID;
            g_WT2[idx] = Wout[o * OC + c * NH + h];
        }
        return;
    }

    // ---------------- QKV block: one (b,g,i) row of 28 ----------------
    __shared__ float xs[CIN * Ww];
    int r = blockIdx.x;
    int i = r % Hh; r /= Hh;
    int g = r & 3;  int b = r >> 2;

    for (int idx = tid; idx < CIN * Ww; idx += 192)
        xs[idx] = x[((b * CIN + idx / Ww) * Gg + g) * HW + i * Ww + (idx % Ww)];
    __syncthreads();

    int h = tid / MID, c = tid % MID;
    int oo = c * NH + h;                          // original channel index
    int wbase = (((b * NH + h) * Gg + g) * HW + i * Ww) * MID + c;

#define CONV_PASS(WM, BM, DST, SCL)                                          \
    {                                                                        \
        float w[CIN];                                                        \
        _Pragma("unroll")                                                    \
        for (int ci = 0; ci < CIN; ci++) w[ci] = WM[oo * CIN + ci];          \
        float a[Ww];                                                         \
        float bias = BM[oo];                                                 \
        _Pragma("unroll")                                                    \
        for (int j = 0; j < Ww; j++) a[j] = bias;                            \
        _Pragma("unroll")                                                    \
        for (int ci = 0; ci < CIN; ci++) {                                   \
            float wv = w[ci];                                                \
            _Pragma("unroll")                                                \
            for (int j = 0; j < Ww; j++) a[j] += wv * xs[ci * Ww + j];       \
        }                                                                    \
        _Pragma("unroll")                                                    \
        for (int j = 0; j < Ww; j++) ws[DST + wbase + j * MID] = a[j] * SCL; \
    }

    CONV_PASS(Wq, bq, QOFF, 1.0f)
    CONV_PASS(Wk, bk, KOFF, INV_SQN)
    CONV_PASS(Wv, bv, VOFF, 1.0f)
#undef CONV_PASS
}

// ---------------------------------------------------------------- kernel 2
// attention: block = 4 waves = positions (i, j0..j0+3) for one (b,h).
// K staged all-m as bf16 (cell-major); V staged per-m fp32 in the same buffer.
__global__ __launch_bounds__(256, 4) void attn_kernel(float* __restrict__ ws)
{
    __shared__ unsigned kvb[7280];                 // 29120 B: K bf16 [m][cell][26u2] / V fp32 [cell][52]
    __shared__ uint2 ppU[4][Gg * PP];              //  6272 B: [wave][m*49+kl] -> bf16 x4 (v)
    __shared__ __align__(16) float qs[4][OC];      //  3072 B: [wave][g*48+c]
    __shared__ float gsm[4][64];                   //  1024 B: [wave][vg*4+m]

    const int tid  = threadIdx.x;
    const int wave = tid >> 6;
    const int lane = tid & 63;

    int blk = blockIdx.x;                  // ((bh)*28 + i)*7 + j0/4
    int j0 = (blk % 7) * 4;
    int i  = (blk / 7) % Hh;
    int bh = blk / (7 * Hh);
    int b = bh >> 2, h = bh & 3;
    int j  = j0 + wave;
    int ij = i * Ww + j;

    const float* Qt  = ws + QOFF;
    const float* Kbh = ws + KOFF + (size_t)bh * Gg * HW * MID;
    const float* Vbh = ws + VOFF + (size_t)bh * Gg * HW * MID;
    float* Ot = ws + OOFF;

    // ---- q (raw; scale folded into K/peT/geT) ----
    #pragma unroll
    for (int s = 0; s < 3; s++) {
        int t = lane + 64 * s;                  // t = g*48+c
        qs[wave][t] = Qt[((size_t)(bh * Gg + (t / MID)) * HW + ij) * MID + (t % MID)];
    }

    // ---- stage all-m K tile as bf16, cell-major ----
    for (int t = tid; t < 3360; t += 256) {
        int c4 = t % 12; int cell = (t / 12) % 70; int m = t / 840;
        int gy = i - 3 + cell / 10, gx = j0 - 3 + cell % 10;
        float4 val = {0.f, 0.f, 0.f, 0.f};
        if ((unsigned)gy < Hh && (unsigned)gx < Ww)
            val = *(const float4*)&Kbh[((size_t)(m * HW + gy * Ww + gx)) * MID + c4 * 4];
        *(uint2*)&kvb[(m * 70 + cell) * 26 + c4 * 2] = make_uint2(pack2(val.x, val.y),
                                                                  pack2(val.z, val.w));
    }
    __syncthreads();

    // ---- per-lane geometry (lane = kl) ----
    int kk = lane / Pp, ll = lane % Pp;
    int cell = (lane < PP) ? kk * 10 + ll + wave : 0;
    bool vmask = (lane < PP) && ((unsigned)(i + kk - 3) < Hh) && ((unsigned)(j + ll - 3) < Ww);

    // ---- pe scores in registers (lane computes & consumes its own kl) ----
    float per[4][4] = {};                          // [v][g]
    if (lane < PP) {
        for (int c = 0; c < 32; c++) {
            float q0 = qs[wave][0 * MID + c], q1 = qs[wave][1 * MID + c];
            float q2 = qs[wave][2 * MID + c], q3 = qs[wave][3 * MID + c];
            #pragma unroll
            for (int v = 0; v < 4; v++) {
                float pk = g_peT[(v * 32 + c) * PP + lane];
                per[v][0] += pk * q0; per[v][1] += pk * q1;
                per[v][2] += pk * q2; per[v][3] += pk * q3;
            }
        }
    }

    // ---- group scores: lane = vg*4+m ----
    {
        int g = (lane >> 2) & 3;
        float ga = 0.f;
        #pragma unroll
        for (int c = 0; c < 16; c++) ga += g_geT[c * 64 + lane] * qs[wave][g * MID + 32 + c];
        gsm[wave][lane] = ga;
    }

    // ---- content: c4-outer, q in registers, bf16 K reads ----
    float acc[4][4] = {};                          // [m][g]
    const float4* qs4 = (const float4*)&qs[wave][0];   // [g*12+c4]
    #pragma unroll
    for (int c4 = 0; c4 < 12; c4++) {
        float4 q0 = qs4[0 * 12 + c4], q1 = qs4[1 * 12 + c4];
        float4 q2 = qs4[2 * 12 + c4], q3 = qs4[3 * 12 + c4];
        #pragma unroll
        for (int m = 0; m < 4; m++) {
            uint2 kp = *(const uint2*)&kvb[(m * 70 + cell) * 26 + c4 * 2];
            float k0 = __uint_as_float(kp.x << 16);
            float k1 = __uint_as_float(kp.x & 0xffff0000u);
            float k2 = __uint_as_float(kp.y << 16);
            float k3 = __uint_as_float(kp.y & 0xffff0000u);
            acc[m][0] += k0 * q0.x + k1 * q0.y + k2 * q0.z + k3 * q0.w;
            acc[m][1] += k0 * q1.x + k1 * q1.y + k2 * q1.z + k3 * q1.w;
            acc[m][2] += k0 * q2.x + k1 * q2.y + k2 * q2.z + k3 * q2.w;
            acc[m][3] += k0 * q3.x + k1 * q3.y + k2 * q3.z + k3 * q3.w;
        }
    }

    // ---- softmax per (v,g), no max-shift (scores O(1)); accumulate over g ----
    float ppr[4][4] = {};                          // [v][m]
    #pragma unroll
    for (int v = 0; v < 4; v++) {
        #pragma unroll
        for (int g = 0; g < 4; g++) {
            int vg = v * 4 + g;
            float ex[4]; float ls = 0.f;
            #pragma unroll
            for (int m = 0; m < 4; m++) {
                float sv = acc[m][g] + per[v][g] + gsm[wave][vg * 4 + m];
                ex[m] = vmask ? __expf(sv) : 0.f;
                ls += ex[m];
            }
            #pragma unroll
            for (int d = 32; d > 0; d >>= 1) ls += __shfl_xor(ls, d, 64);
            float rinv = 1.0f / ls;
            #pragma unroll
            for (int m = 0; m < 4; m++) ppr[v][m] += ex[m] * rinv;
        }
    }
    if (lane < PP) {
        #pragma unroll
        for (int m = 0; m < 4; m++)
            ppU[wave][m * PP + lane] = make_uint2(pack2(ppr[0][m], ppr[1][m]),
                                                  pack2(ppr[2][m], ppr[3][m]));
    }
    __syncthreads();   // content/K reads done; safe to overwrite kvb with V

    // ---- PV: stage V[m] fp32 into kvb; lane = c (<48) ----
    float* vt = (float*)kvb;
    float o0 = 0.f, o1 = 0.f, o2 = 0.f, o3 = 0.f;
    int kklo = i < 3 ? 3 - i : 0, kkhi = i > Hh - 4 ? Hh + 2 - i : 6;
    int lllo = j < 3 ? 3 - j : 0, llhi = j > Ww - 4 ? Ww + 2 - j : 6;

    for (int m = 0; m < Gg; m++) {
        for (int t = tid; t < 840; t += 256) {
            int c4 = t % 12, cl = t / 12;
            int gy = i - 3 + cl / 10, gx = j0 - 3 + cl % 10;
            float4 val = {0.f, 0.f, 0.f, 0.f};
            if ((unsigned)gy < Hh && (unsigned)gx < Ww)
                val = *(const float4*)&Vbh[((size_t)(m * HW + gy * Ww + gx)) * MID + c4 * 4];
            *(float4*)&vt[cl * 52 + c4 * 4] = val;
        }
        __syncthreads();
        if (lane < MID) {
            for (int k2 = kklo; k2 <= kkhi; k2++) {
                #pragma unroll
                for (int l2 = 0; l2 < Pp; l2++) {
                    if (l2 < lllo || l2 > llhi) continue;
                    float vv = vt[(k2 * 10 + l2 + wave) * 52 + lane];
                    uint2 pu = ppU[wave][m * PP + k2 * Pp + l2];
                    o0 += __uint_as_float(pu.x << 16)          * vv;
                    o1 += __uint_as_float(pu.x & 0xffff0000u)  * vv;
                    o2 += __uint_as_float(pu.y << 16)          * vv;
                    o3 += __uint_as_float(pu.y & 0xffff0000u)  * vv;
                }
            }
        }
        __syncthreads();
    }

    if (lane < MID) {
        Ot[((size_t)(b * Gg + 0) * HW + ij) * OC + h * MID + lane] = o0;
        Ot[((size_t)(b * Gg + 1) * HW + ij) * OC + h * MID + lane] = o1;
        Ot[((size_t)(b * Gg + 2) * HW + ij) * OC + h * MID + lane] = o2;
        Ot[((size_t)(b * Gg + 3) * HW + ij) * OC + h * MID + lane] = o3;
    }
}

// ---------------------------------------------------------------- kernel 3
__global__ __launch_bounds__(256) void outproj_kernel(const float* __restrict__ bout,
                                                      const float* __restrict__ ws,
                                                      float* __restrict__ out)
{
    __shared__ float ov[16 * 193];
    __shared__ float res[64 * 17];
    int tid = threadIdx.x;
    int p0 = blockIdx.x * 16;
    const float* Ot = ws + OOFF;

    for (int idx = tid; idx < 16 * OC; idx += 256) {
        int pl = idx / OC, t = idx % OC;
        ov[pl * 193 + t] = Ot[(size_t)(p0 + pl) * OC + t];
    }
    __syncthreads();

    int o = tid & 63, pg = tid >> 6;
    float a0 = bout[o], a1 = a0, a2 = a0, a3 = a0;
    for (int t = 0; t < OC; t++) {
        float w = g_WT2[t * 64 + o];
        a0 += w * ov[(pg     ) * 193 + t];
        a1 += w * ov[(pg +  4) * 193 + t];
        a2 += w * ov[(pg +  8) * 193 + t];
        a3 += w * ov[(pg + 12) * 193 + t];
    }
    res[o * 17 + pg     ] = a0;
    res[o * 17 + pg +  4] = a1;
    res[o * 17 + pg +  8] = a2;
    res[o * 17 + pg + 12] = a3;
    __syncthreads();

    for (int idx = tid; idx < 1024; idx += 256) {
        int o2 = idx >> 4, pl = idx & 15;
        int p = p0 + pl;
        int ij2 = p % HW; int bv = p / HW; int v = bv & 3; int bb = bv >> 2;
        out[((bb * COUT + o2) * Gg + v) * HW + ij2] = res[o2 * 17 + pl];
    }
}

// ---------------------------------------------------------------- launch
extern "C" void kernel_launch(void* const* d_in, const int* in_sizes, int n_in,
                              void* d_out, int out_size, void* d_ws, size_t ws_size,
                              hipStream_t stream)
{
    const float* x      = (const float*)d_in[0];
    const float* Wq     = (const float*)d_in[1];
    const float* bq     = (const float*)d_in[2];
    const float* Wk     = (const float*)d_in[3];
    const float* bk     = (const float*)d_in[4];
    const float* Wv     = (const float*)d_in[5];
    const float* bv     = (const float*)d_in[6];
    const float* Wout   = (const float*)d_in[7];
    const float* bout   = (const float*)d_in[8];
    const float* row_w1 = (const float*)d_in[9];
    const float* row_b1 = (const float*)d_in[10];
    const float* row_g  = (const float*)d_in[11];
    const float* row_bb = (const float*)d_in[12];
    const float* row_w2 = (const float*)d_in[13];
    const float* row_b2 = (const float*)d_in[14];
    const float* col_w1 = (const float*)d_in[15];
    const float* col_b1 = (const float*)d_in[16];
    const float* col_g  = (const float*)d_in[17];
    const float* col_bb = (const float*)d_in[18];
    const float* col_w2 = (const float*)d_in[19];
    const float* col_b2 = (const float*)d_in[20];
    const float* gemb   = (const float*)d_in[21];
    const float* ridx   = (const float*)d_in[22];
    const float* cidx   = (const float*)d_in[23];
    const int*   gidx   = (const int*)d_in[24];

    float* ws  = (float*)d_ws;
    float* out = (float*)d_out;

    qkvpe_kernel<<<Bb * Gg * Hh + 1, 192, 0, stream>>>(
        x, Wq, bq, Wk, bk, Wv, bv,
        row_w1, row_b1, row_g, row_bb, row_w2, row_b2,
        col_w1, col_b1, col_g, col_bb, col_w2, col_b2,
        ridx, cidx, gemb, gidx, Wout, ws);
    attn_kernel<<<Bb * NH * Hh * (Ww / 4), 256, 0, stream>>>(ws);
    outproj_kernel<<<Bb * Gg * HW / 16, 256, 0, stream>>>(bout, ws, out);
}

// Round 5
// 367.883 us; speedup vs baseline: 2.6043x; 2.6043x over previous
//
#include <hip/hip_runtime.h>
#include <math.h>

#define Bb   2
#define CIN  32
#define Gg   4
#define NH   4
#define Hh   28
#define Ww   28
#define HW   784
#define Pp   7
#define PP   49
#define MID  48
#define COUT 64
#define OC   192   // MID*NH

// workspace offsets (floats); Q/K/V/O all [bh][g][ij][c] row-major
#define QOFF  0
#define KOFF  1204224
#define VOFF  2408448
#define OOFF  3612672

#define INV_SQN 0.17677669529663687f

// small precomputed tables (recomputed every call by the table block of qkvpe)
__device__ float g_peT[Gg * 32 * PP];   // [v][c(0..31)][kl], pre-scaled by 1/sqrt(32)
__device__ float g_geT[16 * 64];        // [c][v*16+g*4+m],  pre-scaled by 1/sqrt(32)
__device__ float g_WT2[OC * COUT];      // [h*48+c][o], permuted Wout

__device__ __forceinline__ unsigned bf16rne(float f) {
    unsigned u = __float_as_uint(f);
    return (u + 0x7fffu + ((u >> 16) & 1u)) >> 16;
}
__device__ __forceinline__ unsigned pack2(float a, float b) {
    return bf16rne(a) | (bf16rne(b) << 16);
}

// ---------------------------------------------------------------- kernel 1
// fused QKV 1x1 conv (blocks 0..223) + table setup (block 224)
// NOTE: round-3 loop structure (3-pass pointer arrays, ci loop NOT unrolled) —
// the round-4 fully-unrolled macro version spilled to scratch (+300 us).
__global__ __launch_bounds__(192) void qkvpe_kernel(const float* __restrict__ x,
    const float* __restrict__ Wq, const float* __restrict__ bq,
    const float* __restrict__ Wk, const float* __restrict__ bk,
    const float* __restrict__ Wv, const float* __restrict__ bv,
    const float* row_w1, const float* row_b1,
    const float* row_g,  const float* row_bb,
    const float* row_w2, const float* row_b2,
    const float* col_w1, const float* col_b1,
    const float* col_g,  const float* col_bb,
    const float* col_w2, const float* col_b2,
    const float* row_idx, const float* col_idx,
    const float* group_emb, const int* g_indices,
    const float* Wout,
    float* __restrict__ ws)
{
    int tid = threadIdx.x;
    if (blockIdx.x == Bb * Gg * Hh) {
        // ---------------- table block ----------------
        for (int t = tid; t < 2 * Gg * PP; t += 192) {
            int half = t / (Gg * PP);
            int n    = t - half * (Gg * PP);      // v*49 + kl
            int v = n / PP, kl = n % PP;
            const float* w1 = half ? col_w1 : row_w1;
            const float* b1 = half ? col_b1 : row_b1;
            const float* lg = half ? col_g  : row_g;
            const float* lb = half ? col_bb : row_bb;
            const float* w2 = half ? col_w2 : row_w2;
            const float* b2 = half ? col_b2 : row_b2;
            float tv = half ? col_idx[n] : row_idx[n];

            float hb[16];
            float mean = 0.f;
            for (int k = 0; k < 16; k++) { hb[k] = tv * w1[k] + b1[k]; mean += hb[k]; }
            mean *= (1.f / 16.f);
            float var = 0.f;
            for (int k = 0; k < 16; k++) { float d = hb[k] - mean; var += d * d; }
            var *= (1.f / 16.f);
            float inv = 1.f / sqrtf(var + 1e-5f);
            for (int k = 0; k < 16; k++) {
                float hn = (hb[k] - mean) * inv * lg[k] + lb[k];
                hb[k] = hn / (1.f + expf(-hn));
            }
            for (int p = 0; p < 16; p++) {
                float acc = b2[p];
                for (int k = 0; k < 16; k++) acc += hb[k] * w2[p * 16 + k];
                g_peT[(v * 32 + half * 16 + p) * PP + kl] = acc * INV_SQN;
            }
        }
        for (int t = tid; t < 64; t += 192) {
            int gi = g_indices[t];
            for (int c = 0; c < 16; c++)
                g_geT[c * 64 + t] = group_emb[gi * 16 + c] * INV_SQN;
        }
        for (int idx = tid; idx < OC * COUT; idx += 192) {
            int tp = idx >> 6, o = idx & 63;      // tp = h*48+c
            int h = tp / MID, c = tp % MID;
            g_WT2[idx] = Wout[o * OC + c * NH + h];
        }
        return;
    }

    // ---------------- QKV block: one (b,g,i) row of 28 ----------------
    __shared__ float xs[CIN * Ww];
    int r = blockIdx.x;
    int i = r % Hh; r /= Hh;
    int g = r & 3;  int b = r >> 2;

    for (int idx = tid; idx < CIN * Ww; idx += 192)
        xs[idx] = x[((b * CIN + idx / Ww) * Gg + g) * HW + i * Ww + (idx % Ww)];
    __syncthreads();

    int h = tid / MID, c = tid % MID;
    int oo = c * NH + h;                          // original channel index
    int wbase = (((b * NH + h) * Gg + g) * HW + i * Ww) * MID + c;

    const float* Wm[3]  = {Wq, Wk, Wv};
    const float* bm[3]  = {bq, bk, bv};
    const int    off[3] = {QOFF, KOFF, VOFF};
    const float  scl[3] = {1.0f, INV_SQN, 1.0f};
    for (int p = 0; p < 3; p++) {
        float w[CIN];
        #pragma unroll
        for (int ci = 0; ci < CIN; ci++) w[ci] = Wm[p][oo * CIN + ci];
        float bias = bm[p][oo];
        float a[Ww];
        #pragma unroll
        for (int j = 0; j < Ww; j++) a[j] = bias;
        for (int ci = 0; ci < CIN; ci++) {
            float wv = w[ci];
            #pragma unroll
            for (int j = 0; j < Ww; j++) a[j] += wv * xs[ci * Ww + j];
        }
        float s = scl[p];
        #pragma unroll
        for (int j = 0; j < Ww; j++) ws[off[p] + wbase + j * MID] = a[j] * s;
    }
}

// ---------------------------------------------------------------- kernel 2
// attention: block = 4 waves = positions (i, j0..j0+3) for one (b,h).
// K staged all-m as bf16 (cell-major); V staged per-m fp32 in the same buffer.
// NO min-waves clamp: __launch_bounds__(256,4) forced VGPR=64 + massive
// scratch spills (round 4: 1.2 GB HBM traffic). LDS 39.5 KB already caps
// occupancy at 4 blocks/CU, which fits a <=128-VGPR allocation.
__global__ __launch_bounds__(256) void attn_kernel(float* __restrict__ ws)
{
    __shared__ unsigned kvb[7280];                 // 29120 B: K bf16 [m][cell][26u2] / V fp32 [cell][52]
    __shared__ uint2 ppU[4][Gg * PP];              //  6272 B: [wave][m*49+kl] -> bf16 x4 (v)
    __shared__ __align__(16) float qs[4][OC];      //  3072 B: [wave][g*48+c]
    __shared__ float gsm[4][64];                   //  1024 B: [wave][vg*4+m]

    const int tid  = threadIdx.x;
    const int wave = tid >> 6;
    const int lane = tid & 63;

    int blk = blockIdx.x;                  // ((bh)*28 + i)*7 + j0/4
    int j0 = (blk % 7) * 4;
    int i  = (blk / 7) % Hh;
    int bh = blk / (7 * Hh);
    int b = bh >> 2, h = bh & 3;
    int j  = j0 + wave;
    int ij = i * Ww + j;

    const float* Qt  = ws + QOFF;
    const float* Kbh = ws + KOFF + (size_t)bh * Gg * HW * MID;
    const float* Vbh = ws + VOFF + (size_t)bh * Gg * HW * MID;
    float* Ot = ws + OOFF;

    // ---- q (raw; scale folded into K/peT/geT) ----
    #pragma unroll
    for (int s = 0; s < 3; s++) {
        int t = lane + 64 * s;                  // t = g*48+c
        qs[wave][t] = Qt[((size_t)(bh * Gg + (t / MID)) * HW + ij) * MID + (t % MID)];
    }

    // ---- stage all-m K tile as bf16, cell-major ----
    for (int t = tid; t < 3360; t += 256) {
        int c4 = t % 12; int cell = (t / 12) % 70; int m = t / 840;
        int gy = i - 3 + cell / 10, gx = j0 - 3 + cell % 10;
        float4 val = {0.f, 0.f, 0.f, 0.f};
        if ((unsigned)gy < Hh && (unsigned)gx < Ww)
            val = *(const float4*)&Kbh[((size_t)(m * HW + gy * Ww + gx)) * MID + c4 * 4];
        *(uint2*)&kvb[(m * 70 + cell) * 26 + c4 * 2] = make_uint2(pack2(val.x, val.y),
                                                                  pack2(val.z, val.w));
    }
    __syncthreads();

    // ---- per-lane geometry (lane = kl) ----
    int kk = lane / Pp, ll = lane % Pp;
    int cell = (lane < PP) ? kk * 10 + ll + wave : 0;
    bool vmask = (lane < PP) && ((unsigned)(i + kk - 3) < Hh) && ((unsigned)(j + ll - 3) < Ww);

    // ---- pe scores in registers (lane computes & consumes its own kl) ----
    float per[4][4] = {};                          // [v][g]
    if (lane < PP) {
        for (int c = 0; c < 32; c++) {
            float q0 = qs[wave][0 * MID + c], q1 = qs[wave][1 * MID + c];
            float q2 = qs[wave][2 * MID + c], q3 = qs[wave][3 * MID + c];
            #pragma unroll
            for (int v = 0; v < 4; v++) {
                float pk = g_peT[(v * 32 + c) * PP + lane];
                per[v][0] += pk * q0; per[v][1] += pk * q1;
                per[v][2] += pk * q2; per[v][3] += pk * q3;
            }
        }
    }

    // ---- group scores: lane = vg*4+m ----
    {
        int g = (lane >> 2) & 3;
        float ga = 0.f;
        #pragma unroll
        for (int c = 0; c < 16; c++) ga += g_geT[c * 64 + lane] * qs[wave][g * MID + 32 + c];
        gsm[wave][lane] = ga;
    }

    // ---- content: c4-outer, q in registers, bf16 K reads ----
    float acc[4][4] = {};                          // [m][g]
    const float4* qs4 = (const float4*)&qs[wave][0];   // [g*12+c4]
    #pragma unroll
    for (int c4 = 0; c4 < 12; c4++) {
        float4 q0 = qs4[0 * 12 + c4], q1 = qs4[1 * 12 + c4];
        float4 q2 = qs4[2 * 12 + c4], q3 = qs4[3 * 12 + c4];
        #pragma unroll
        for (int m = 0; m < 4; m++) {
            uint2 kp = *(const uint2*)&kvb[(m * 70 + cell) * 26 + c4 * 2];
            float k0 = __uint_as_float(kp.x << 16);
            float k1 = __uint_as_float(kp.x & 0xffff0000u);
            float k2 = __uint_as_float(kp.y << 16);
            float k3 = __uint_as_float(kp.y & 0xffff0000u);
            acc[m][0] += k0 * q0.x + k1 * q0.y + k2 * q0.z + k3 * q0.w;
            acc[m][1] += k0 * q1.x + k1 * q1.y + k2 * q1.z + k3 * q1.w;
            acc[m][2] += k0 * q2.x + k1 * q2.y + k2 * q2.z + k3 * q2.w;
            acc[m][3] += k0 * q3.x + k1 * q3.y + k2 * q3.z + k3 * q3.w;
        }
    }

    // ---- softmax per (v,g), no max-shift (scores O(1)); accumulate over g ----
    float ppr[4][4] = {};                          // [v][m]
    #pragma unroll
    for (int v = 0; v < 4; v++) {
        #pragma unroll
        for (int g = 0; g < 4; g++) {
            int vg = v * 4 + g;
            float ex[4]; float ls = 0.f;
            #pragma unroll
            for (int m = 0; m < 4; m++) {
                float sv = acc[m][g] + per[v][g] + gsm[wave][vg * 4 + m];
                ex[m] = vmask ? __expf(sv) : 0.f;
                ls += ex[m];
            }
            #pragma unroll
            for (int d = 32; d > 0; d >>= 1) ls += __shfl_xor(ls, d, 64);
            float rinv = 1.0f / ls;
            #pragma unroll
            for (int m = 0; m < 4; m++) ppr[v][m] += ex[m] * rinv;
        }
    }
    if (lane < PP) {
        #pragma unroll
        for (int m = 0; m < 4; m++)
            ppU[wave][m * PP + lane] = make_uint2(pack2(ppr[0][m], ppr[1][m]),
                                                  pack2(ppr[2][m], ppr[3][m]));
    }
    __syncthreads();   // content/K reads done; safe to overwrite kvb with V

    // ---- PV: stage V[m] fp32 into kvb; lane = c (<48) ----
    float* vt = (float*)kvb;
    float o0 = 0.f, o1 = 0.f, o2 = 0.f, o3 = 0.f;
    int kklo = i < 3 ? 3 - i : 0, kkhi = i > Hh - 4 ? Hh + 2 - i : 6;
    int lllo = j < 3 ? 3 - j : 0, llhi = j > Ww - 4 ? Ww + 2 - j : 6;

    for (int m = 0; m < Gg; m++) {
        for (int t = tid; t < 840; t += 256) {
            int c4 = t % 12, cl = t / 12;
            int gy = i - 3 + cl / 10, gx = j0 - 3 + cl % 10;
            float4 val = {0.f, 0.f, 0.f, 0.f};
            if ((unsigned)gy < Hh && (unsigned)gx < Ww)
                val = *(const float4*)&Vbh[((size_t)(m * HW + gy * Ww + gx)) * MID + c4 * 4];
            *(float4*)&vt[cl * 52 + c4 * 4] = val;
        }
        __syncthreads();
        if (lane < MID) {
            for (int k2 = kklo; k2 <= kkhi; k2++) {
                #pragma unroll
                for (int l2 = 0; l2 < Pp; l2++) {
                    if (l2 < lllo || l2 > llhi) continue;
                    float vv = vt[(k2 * 10 + l2 + wave) * 52 + lane];
                    uint2 pu = ppU[wave][m * PP + k2 * Pp + l2];
                    o0 += __uint_as_float(pu.x << 16)          * vv;
                    o1 += __uint_as_float(pu.x & 0xffff0000u)  * vv;
                    o2 += __uint_as_float(pu.y << 16)          * vv;
                    o3 += __uint_as_float(pu.y & 0xffff0000u)  * vv;
                }
            }
        }
        __syncthreads();
    }

    if (lane < MID) {
        Ot[((size_t)(b * Gg + 0) * HW + ij) * OC + h * MID + lane] = o0;
        Ot[((size_t)(b * Gg + 1) * HW + ij) * OC + h * MID + lane] = o1;
        Ot[((size_t)(b * Gg + 2) * HW + ij) * OC + h * MID + lane] = o2;
        Ot[((size_t)(b * Gg + 3) * HW + ij) * OC + h * MID + lane] = o3;
    }
}

// ---------------------------------------------------------------- kernel 3
__global__ __launch_bounds__(256) void outproj_kernel(const float* __restrict__ bout,
                                                      const float* __restrict__ ws,
                                                      float* __restrict__ out)
{
    __shared__ float ov[16 * 193];
    __shared__ float res[64 * 17];
    int tid = threadIdx.x;
    int p0 = blockIdx.x * 16;
    const float* Ot = ws + OOFF;

    for (int idx = tid; idx < 16 * OC; idx += 256) {
        int pl = idx / OC, t = idx % OC;
        ov[pl * 193 + t] = Ot[(size_t)(p0 + pl) * OC + t];
    }
    __syncthreads();

    int o = tid & 63, pg = tid >> 6;
    float a0 = bout[o], a1 = a0, a2 = a0, a3 = a0;
    for (int t = 0; t < OC; t++) {
        float w = g_WT2[t * 64 + o];
        a0 += w * ov[(pg     ) * 193 + t];
        a1 += w * ov[(pg +  4) * 193 + t];
        a2 += w * ov[(pg +  8) * 193 + t];
        a3 += w * ov[(pg + 12) * 193 + t];
    }
    res[o * 17 + pg     ] = a0;
    res[o * 17 + pg +  4] = a1;
    res[o * 17 + pg +  8] = a2;
    res[o * 17 + pg + 12] = a3;
    __syncthreads();

    for (int idx = tid; idx < 1024; idx += 256) {
        int o2 = idx >> 4, pl = idx & 15;
        int p = p0 + pl;
        int ij2 = p % HW; int bv = p / HW; int v = bv & 3; int bb = bv >> 2;
        out[((bb * COUT + o2) * Gg + v) * HW + ij2] = res[o2 * 17 + pl];
    }
}

// ---------------------------------------------------------------- launch
extern "C" void kernel_launch(void* const* d_in, const int* in_sizes, int n_in,
                              void* d_out, int out_size, void* d_ws, size_t ws_size,
                              hipStream_t stream)
{
    const float* x      = (const float*)d_in[0];
    const float* Wq     = (const float*)d_in[1];
    const float* bq     = (const float*)d_in[2];
    const float* Wk     = (const float*)d_in[3];
    const float* bk     = (const float*)d_in[4];
    const float* Wv     = (const float*)d_in[5];
    const float* bv     = (const float*)d_in[6];
    const float* Wout   = (const float*)d_in[7];
    const float* bout   = (const float*)d_in[8];
    const float* row_w1 = (const float*)d_in[9];
    const float* row_b1 = (const float*)d_in[10];
    const float* row_g  = (const float*)d_in[11];
    const float* row_bb = (const float*)d_in[12];
    const float* row_w2 = (const float*)d_in[13];
    const float* row_b2 = (const float*)d_in[14];
    const float* col_w1 = (const float*)d_in[15];
    const float* col_b1 = (const float*)d_in[16];
    const float* col_g  = (const float*)d_in[17];
    const float* col_bb = (const float*)d_in[18];
    const float* col_w2 = (const float*)d_in[19];
    const float* col_b2 = (const float*)d_in[20];
    const float* gemb   = (const float*)d_in[21];
    const float* ridx   = (const float*)d_in[22];
    const float* cidx   = (const float*)d_in[23];
    const int*   gidx   = (const int*)d_in[24];

    float* ws  = (float*)d_ws;
    float* out = (float*)d_out;

    qkvpe_kernel<<<Bb * Gg * Hh + 1, 192, 0, stream>>>(
        x, Wq, bq, Wk, bk, Wv, bv,
        row_w1, row_b1, row_g, row_bb, row_w2, row_b2,
        col_w1, col_b1, col_g, col_bb, col_w2, col_b2,
        ridx, cidx, gemb, gidx, Wout, ws);
    attn_kernel<<<Bb * NH * Hh * (Ww / 4), 256, 0, stream>>>(ws);
    outproj_kernel<<<Bb * Gg * HW / 16, 256, 0, stream>>>(bout, ws, out);
}

// Round 6
// 228.061 us; speedup vs baseline: 4.2010x; 1.6131x over previous
//
#include <hip/hip_runtime.h>
#include <math.h>

#define Bb   2
#define CIN  32
#define Gg   4
#define NH   4
#define Hh   28
#define Ww   28
#define HW   784
#define Pp   7
#define PP   49
#define MID  48
#define COUT 64
#define OC   192   // MID*NH

// workspace offsets (floats); Q/K/V/O all [bh][g][ij][c] row-major
#define QOFF  0
#define KOFF  1204224
#define VOFF  2408448
#define OOFF  3612672

#define INV_SQN 0.17677669529663687f

// small precomputed tables (recomputed every call by the table block of qkvpe)
__device__ float g_peT[Gg * 32 * PP];   // [v][c(0..31)][kl], pre-scaled by 1/sqrt(32)
__device__ float g_geT[16 * 64];        // [c][v*16+g*4+m],  pre-scaled by 1/sqrt(32)
__device__ float g_WT2[OC * COUT];      // [h*48+c][o], permuted Wout

__device__ __forceinline__ unsigned bf16rne(float f) {
    unsigned u = __float_as_uint(f);
    return (u + 0x7fffu + ((u >> 16) & 1u)) >> 16;
}
__device__ __forceinline__ unsigned pack2(float a, float b) {
    return bf16rne(a) | (bf16rne(b) << 16);
}

// ---------------------------------------------------------------- kernel 1
// fused QKV 1x1 conv (blocks 0..223) + table setup (block 224)
// round-3 loop structure (3-pass pointer arrays, ci loop NOT unrolled) —
// the fully-unrolled macro version spilled to scratch (+300 us, round 4).
__global__ __launch_bounds__(192) void qkvpe_kernel(const float* __restrict__ x,
    const float* __restrict__ Wq, const float* __restrict__ bq,
    const float* __restrict__ Wk, const float* __restrict__ bk,
    const float* __restrict__ Wv, const float* __restrict__ bv,
    const float* row_w1, const float* row_b1,
    const float* row_g,  const float* row_bb,
    const float* row_w2, const float* row_b2,
    const float* col_w1, const float* col_b1,
    const float* col_g,  const float* col_bb,
    const float* col_w2, const float* col_b2,
    const float* row_idx, const float* col_idx,
    const float* group_emb, const int* g_indices,
    const float* Wout,
    float* __restrict__ ws)
{
    int tid = threadIdx.x;
    if (blockIdx.x == Bb * Gg * Hh) {
        // ---------------- table block ----------------
        for (int t = tid; t < 2 * Gg * PP; t += 192) {
            int half = t / (Gg * PP);
            int n    = t - half * (Gg * PP);      // v*49 + kl
            int v = n / PP, kl = n % PP;
            const float* w1 = half ? col_w1 : row_w1;
            const float* b1 = half ? col_b1 : row_b1;
            const float* lg = half ? col_g  : row_g;
            const float* lb = half ? col_bb : row_bb;
            const float* w2 = half ? col_w2 : row_w2;
            const float* b2 = half ? col_b2 : row_b2;
            float tv = half ? col_idx[n] : row_idx[n];

            float hb[16];
            float mean = 0.f;
            for (int k = 0; k < 16; k++) { hb[k] = tv * w1[k] + b1[k]; mean += hb[k]; }
            mean *= (1.f / 16.f);
            float var = 0.f;
            for (int k = 0; k < 16; k++) { float d = hb[k] - mean; var += d * d; }
            var *= (1.f / 16.f);
            float inv = 1.f / sqrtf(var + 1e-5f);
            for (int k = 0; k < 16; k++) {
                float hn = (hb[k] - mean) * inv * lg[k] + lb[k];
                hb[k] = hn / (1.f + expf(-hn));
            }
            for (int p = 0; p < 16; p++) {
                float acc = b2[p];
                for (int k = 0; k < 16; k++) acc += hb[k] * w2[p * 16 + k];
                g_peT[(v * 32 + half * 16 + p) * PP + kl] = acc * INV_SQN;
            }
        }
        for (int t = tid; t < 64; t += 192) {
            int gi = g_indices[t];
            for (int c = 0; c < 16; c++)
                g_geT[c * 64 + t] = group_emb[gi * 16 + c] * INV_SQN;
        }
        for (int idx = tid; idx < OC * COUT; idx += 192) {
            int tp = idx >> 6, o = idx & 63;      // tp = h*48+c
            int h = tp / MID, c = tp % MID;
            g_WT2[idx] = Wout[o * OC + c * NH + h];
        }
        return;
    }

    // ---------------- QKV block: one (b,g,i) row of 28 ----------------
    __shared__ float xs[CIN * Ww];
    int r = blockIdx.x;
    int i = r % Hh; r /= Hh;
    int g = r & 3;  int b = r >> 2;

    for (int idx = tid; idx < CIN * Ww; idx += 192)
        xs[idx] = x[((b * CIN + idx / Ww) * Gg + g) * HW + i * Ww + (idx % Ww)];
    __syncthreads();

    int h = tid / MID, c = tid % MID;
    int oo = c * NH + h;                          // original channel index
    int wbase = (((b * NH + h) * Gg + g) * HW + i * Ww) * MID + c;

    const float* Wm[3]  = {Wq, Wk, Wv};
    const float* bm[3]  = {bq, bk, bv};
    const int    off[3] = {QOFF, KOFF, VOFF};
    const float  scl[3] = {1.0f, INV_SQN, 1.0f};
    for (int p = 0; p < 3; p++) {
        float w[CIN];
        #pragma unroll
        for (int ci = 0; ci < CIN; ci++) w[ci] = Wm[p][oo * CIN + ci];
        float bias = bm[p][oo];
        float a[Ww];
        #pragma unroll
        for (int j = 0; j < Ww; j++) a[j] = bias;
        for (int ci = 0; ci < CIN; ci++) {
            float wv = w[ci];
            #pragma unroll
            for (int j = 0; j < Ww; j++) a[j] += wv * xs[ci * Ww + j];
        }
        float s = scl[p];
        #pragma unroll
        for (int j = 0; j < Ww; j++) ws[off[p] + wbase + j * MID] = a[j] * s;
    }
}

// ---------------------------------------------------------------- kernel 2
// attention: block = 4 waves = positions (i, j0..j0+3) for one (b,h).
// K staged all-m as bf16 (cell-major); V staged per-m fp32 in the same buffer.
// VGPR discipline (rounds 4/5 lessons):
//  - round 4: clamping a ~200-reg kernel to (256,4) -> VGPR 64 + 1.2 GB spills.
//  - round 5: no clamp + fully-unrolled c4 loop -> compiler hoists all 48 q
//    float4 LDS reads -> VGPR 200 -> 2 waves/SIMD -> 264 us.
//  Fix: unroll-2 windows keep natural demand ~110 regs; (256,4) caps at 128
//  so 4 blocks/CU co-reside (LDS 39.9 KB also allows exactly 4).
__global__ __launch_bounds__(256, 4) void attn_kernel(float* __restrict__ ws)
{
    __shared__ unsigned kvb[7280];                 // 29120 B: K bf16 [m][cell][26u2] / V fp32 [cell][52]
    __shared__ uint2 ppU[4][Gg * PP];              //  6272 B: [wave][m*49+kl] -> bf16 x4 (v)
    __shared__ __align__(16) float qs[4][OC];      //  3072 B: [wave][g*48+c]
    __shared__ float gsm[4][64];                   //  1024 B: [wave][vg*4+m]

    const int tid  = threadIdx.x;
    const int wave = tid >> 6;
    const int lane = tid & 63;

    int blk = blockIdx.x;                  // ((bh)*28 + i)*7 + j0/4
    int j0 = (blk % 7) * 4;
    int i  = (blk / 7) % Hh;
    int bh = blk / (7 * Hh);
    int b = bh >> 2, h = bh & 3;
    int j  = j0 + wave;
    int ij = i * Ww + j;

    const float* Qt  = ws + QOFF;
    const float* Kbh = ws + KOFF + (size_t)bh * Gg * HW * MID;
    const float* Vbh = ws + VOFF + (size_t)bh * Gg * HW * MID;
    float* Ot = ws + OOFF;

    // ---- q (raw; scale folded into K/peT/geT) ----
    #pragma unroll
    for (int s = 0; s < 3; s++) {
        int t = lane + 64 * s;                  // t = g*48+c
        qs[wave][t] = Qt[((size_t)(bh * Gg + (t / MID)) * HW + ij) * MID + (t % MID)];
    }

    // ---- stage all-m K tile as bf16, cell-major ----
    for (int t = tid; t < 3360; t += 256) {
        int c4 = t % 12; int cell = (t / 12) % 70; int m = t / 840;
        int gy = i - 3 + cell / 10, gx = j0 - 3 + cell % 10;
        float4 val = {0.f, 0.f, 0.f, 0.f};
        if ((unsigned)gy < Hh && (unsigned)gx < Ww)
            val = *(const float4*)&Kbh[((size_t)(m * HW + gy * Ww + gx)) * MID + c4 * 4];
        *(uint2*)&kvb[(m * 70 + cell) * 26 + c4 * 2] = make_uint2(pack2(val.x, val.y),
                                                                  pack2(val.z, val.w));
    }

    // ---- per-lane geometry (lane = kl) ----
    int kk = lane / Pp, ll = lane % Pp;
    int cell = (lane < PP) ? kk * 10 + ll + wave : 0;
    bool vmask = (lane < PP) && ((unsigned)(i + kk - 3) < Hh) && ((unsigned)(j + ll - 3) < Ww);
    int lclamp = lane < PP ? lane : 0;

    // ---- pe scores in registers (lane computes & consumes its own kl);
    //      global peT loads overlap the staging loop above (pre-barrier) ----
    float per[4][4] = {};                          // [v][g]
    #pragma unroll 2
    for (int c = 0; c < 32; c++) {
        float q0 = qs[wave][0 * MID + c], q1 = qs[wave][1 * MID + c];
        float q2 = qs[wave][2 * MID + c], q3 = qs[wave][3 * MID + c];
        #pragma unroll
        for (int v = 0; v < 4; v++) {
            float pk = g_peT[(v * 32 + c) * PP + lclamp];
            per[v][0] += pk * q0; per[v][1] += pk * q1;
            per[v][2] += pk * q2; per[v][3] += pk * q3;
        }
    }

    // ---- group scores: lane = vg*4+m ----
    {
        int g = (lane >> 2) & 3;
        float ga = 0.f;
        #pragma unroll
        for (int c = 0; c < 16; c++) ga += g_geT[c * 64 + lane] * qs[wave][g * MID + 32 + c];
        gsm[wave][lane] = ga;
    }
    __syncthreads();

    // ---- content: c4-outer (each K value serves all 4 g), q broadcast reads.
    //      unroll 2: keeps the live q/K window at ~48 regs (round-5 full
    //      unroll hoisted 192 regs of q). ----
    float acc[4][4] = {};                          // [m][g]
    const float4* qs4 = (const float4*)&qs[wave][0];   // [g*12+c4]
    #pragma unroll 2
    for (int c4 = 0; c4 < 12; c4++) {
        float4 q0 = qs4[0 * 12 + c4], q1 = qs4[1 * 12 + c4];
        float4 q2 = qs4[2 * 12 + c4], q3 = qs4[3 * 12 + c4];
        #pragma unroll
        for (int m = 0; m < 4; m++) {
            uint2 kp = *(const uint2*)&kvb[(m * 70 + cell) * 26 + c4 * 2];
            float k0 = __uint_as_float(kp.x << 16);
            float k1 = __uint_as_float(kp.x & 0xffff0000u);
            float k2 = __uint_as_float(kp.y << 16);
            float k3 = __uint_as_float(kp.y & 0xffff0000u);
            acc[m][0] += k0 * q0.x + k1 * q0.y + k2 * q0.z + k3 * q0.w;
            acc[m][1] += k0 * q1.x + k1 * q1.y + k2 * q1.z + k3 * q1.w;
            acc[m][2] += k0 * q2.x + k1 * q2.y + k2 * q2.z + k3 * q2.w;
            acc[m][3] += k0 * q3.x + k1 * q3.y + k2 * q3.z + k3 * q3.w;
        }
    }

    // ---- softmax per (v,g), no max-shift (scores O(1)); accumulate over g ----
    float ppr[4][4] = {};                          // [v][m]
    #pragma unroll
    for (int v = 0; v < 4; v++) {
        #pragma unroll
        for (int g = 0; g < 4; g++) {
            int vg = v * 4 + g;
            float ex[4]; float ls = 0.f;
            #pragma unroll
            for (int m = 0; m < 4; m++) {
                float sv = acc[m][g] + per[v][g] + gsm[wave][vg * 4 + m];
                ex[m] = vmask ? __expf(sv) : 0.f;
                ls += ex[m];
            }
            #pragma unroll
            for (int d = 32; d > 0; d >>= 1) ls += __shfl_xor(ls, d, 64);
            float rinv = 1.0f / ls;
            #pragma unroll
            for (int m = 0; m < 4; m++) ppr[v][m] += ex[m] * rinv;
        }
    }
    if (lane < PP) {
        #pragma unroll
        for (int m = 0; m < 4; m++)
            ppU[wave][m * PP + lane] = make_uint2(pack2(ppr[0][m], ppr[1][m]),
                                                  pack2(ppr[2][m], ppr[3][m]));
    }
    __syncthreads();   // content/K reads done; safe to overwrite kvb with V

    // ---- PV: stage V[m] fp32 into kvb; lane = c (<48) ----
    float* vt = (float*)kvb;
    float o0 = 0.f, o1 = 0.f, o2 = 0.f, o3 = 0.f;
    int kklo = i < 3 ? 3 - i : 0, kkhi = i > Hh - 4 ? Hh + 2 - i : 6;
    int lllo = j < 3 ? 3 - j : 0, llhi = j > Ww - 4 ? Ww + 2 - j : 6;

    for (int m = 0; m < Gg; m++) {
        for (int t = tid; t < 840; t += 256) {
            int c4 = t % 12, cl = t / 12;
            int gy = i - 3 + cl / 10, gx = j0 - 3 + cl % 10;
            float4 val = {0.f, 0.f, 0.f, 0.f};
            if ((unsigned)gy < Hh && (unsigned)gx < Ww)
                val = *(const float4*)&Vbh[((size_t)(m * HW + gy * Ww + gx)) * MID + c4 * 4];
            *(float4*)&vt[cl * 52 + c4 * 4] = val;
        }
        __syncthreads();
        if (lane < MID) {
            for (int k2 = kklo; k2 <= kkhi; k2++) {
                #pragma unroll
                for (int l2 = 0; l2 < Pp; l2++) {
                    if (l2 < lllo || l2 > llhi) continue;
                    float vv = vt[(k2 * 10 + l2 + wave) * 52 + lane];
                    uint2 pu = ppU[wave][m * PP + k2 * Pp + l2];
                    o0 += __uint_as_float(pu.x << 16)          * vv;
                    o1 += __uint_as_float(pu.x & 0xffff0000u)  * vv;
                    o2 += __uint_as_float(pu.y << 16)          * vv;
                    o3 += __uint_as_float(pu.y & 0xffff0000u)  * vv;
                }
            }
        }
        __syncthreads();
    }

    if (lane < MID) {
        Ot[((size_t)(b * Gg + 0) * HW + ij) * OC + h * MID + lane] = o0;
        Ot[((size_t)(b * Gg + 1) * HW + ij) * OC + h * MID + lane] = o1;
        Ot[((size_t)(b * Gg + 2) * HW + ij) * OC + h * MID + lane] = o2;
        Ot[((size_t)(b * Gg + 3) * HW + ij) * OC + h * MID + lane] = o3;
    }
}

// ---------------------------------------------------------------- kernel 3
__global__ __launch_bounds__(256) void outproj_kernel(const float* __restrict__ bout,
                                                      const float* __restrict__ ws,
                                                      float* __restrict__ out)
{
    __shared__ float ov[16 * 193];
    __shared__ float res[64 * 17];
    int tid = threadIdx.x;
    int p0 = blockIdx.x * 16;
    const float* Ot = ws + OOFF;

    for (int idx = tid; idx < 16 * OC; idx += 256) {
        int pl = idx / OC, t = idx % OC;
        ov[pl * 193 + t] = Ot[(size_t)(p0 + pl) * OC + t];
    }
    __syncthreads();

    int o = tid & 63, pg = tid >> 6;
    float a0 = bout[o], a1 = a0, a2 = a0, a3 = a0;
    for (int t = 0; t < OC; t++) {
        float w = g_WT2[t * 64 + o];
        a0 += w * ov[(pg     ) * 193 + t];
        a1 += w * ov[(pg +  4) * 193 + t];
        a2 += w * ov[(pg +  8) * 193 + t];
        a3 += w * ov[(pg + 12) * 193 + t];
    }
    res[o * 17 + pg     ] = a0;
    res[o * 17 + pg +  4] = a1;
    res[o * 17 + pg +  8] = a2;
    res[o * 17 + pg + 12] = a3;
    __syncthreads();

    for (int idx = tid; idx < 1024; idx += 256) {
        int o2 = idx >> 4, pl = idx & 15;
        int p = p0 + pl;
        int ij2 = p % HW; int bv = p / HW; int v = bv & 3; int bb = bv >> 2;
        out[((bb * COUT + o2) * Gg + v) * HW + ij2] = res[o2 * 17 + pl];
    }
}

// ---------------------------------------------------------------- launch
extern "C" void kernel_launch(void* const* d_in, const int* in_sizes, int n_in,
                              void* d_out, int out_size, void* d_ws, size_t ws_size,
                              hipStream_t stream)
{
    const float* x      = (const float*)d_in[0];
    const float* Wq     = (const float*)d_in[1];
    const float* bq     = (const float*)d_in[2];
    const float* Wk     = (const float*)d_in[3];
    const float* bk     = (const float*)d_in[4];
    const float* Wv     = (const float*)d_in[5];
    const float* bv     = (const float*)d_in[6];
    const float* Wout   = (const float*)d_in[7];
    const float* bout   = (const float*)d_in[8];
    const float* row_w1 = (const float*)d_in[9];
    const float* row_b1 = (const float*)d_in[10];
    const float* row_g  = (const float*)d_in[11];
    const float* row_bb = (const float*)d_in[12];
    const float* row_w2 = (const float*)d_in[13];
    const float* row_b2 = (const float*)d_in[14];
    const float* col_w1 = (const float*)d_in[15];
    const float* col_b1 = (const float*)d_in[16];
    const float* col_g  = (const float*)d_in[17];
    const float* col_bb = (const float*)d_in[18];
    const float* col_w2 = (const float*)d_in[19];
    const float* col_b2 = (const float*)d_in[20];
    const float* gemb   = (const float*)d_in[21];
    const float* ridx   = (const float*)d_in[22];
    const float* cidx   = (const float*)d_in[23];
    const int*   gidx   = (const int*)d_in[24];

    float* ws  = (float*)d_ws;
    float* out = (float*)d_out;

    qkvpe_kernel<<<Bb * Gg * Hh + 1, 192, 0, stream>>>(
        x, Wq, bq, Wk, bk, Wv, bv,
        row_w1, row_b1, row_g, row_bb, row_w2, row_b2,
        col_w1, col_b1, col_g, col_bb, col_w2, col_b2,
        ridx, cidx, gemb, gidx, Wout, ws);
    attn_kernel<<<Bb * NH * Hh * (Ww / 4), 256, 0, stream>>>(ws);
    outproj_kernel<<<Bb * Gg * HW / 16, 256, 0, stream>>>(bout, ws, out);
}